// Round 2
// baseline (208.229 us; speedup 1.0000x reference)
//
#include <hip/hip_runtime.h>
#include <hip/hip_bf16.h>

#define BATCH 4
#define SEQ   2048
#define EMB   1024
#define HD    64
#define BT    (BATCH * SEQ)
#define XS_STRIDE 1040   // dword stride 520 = 8 mod 32

// logits scale 1/sqrt(64) folded with log2(e) so softmax can use exp2 directly
#define QSCALE 0.18033688011112042f

typedef __attribute__((ext_vector_type(8))) short bf16x8;
typedef __attribute__((ext_vector_type(4))) float f32x4;

__device__ __forceinline__ ushort f2bf(float f) {   // RTN fp32 -> bf16 bits
    unsigned u = __float_as_uint(f);
    return (ushort)((u + 0x7FFFu + ((u >> 16) & 1u)) >> 16);
}

// ---- prep: Wf = W in MFMA B-fragment order [kc(32)][sub(12)][lane(64)][8] --
// frag element (lane,j): row = sub*16 + (lane&15), e = kc*32 + (lane>>4)*8 + j
// Also zeroes the attn split-K arrival counters (128 tiles).
__global__ __launch_bounds__(256) void prep(
    const float* __restrict__ Wq, const float* __restrict__ bq,
    const float* __restrict__ Wk, const float* __restrict__ bk,
    const float* __restrict__ Wv, const float* __restrict__ bv,
    ushort* __restrict__ Wf, float* __restrict__ bb, uint* __restrict__ cnt)
{
    const int fid = (int)blockIdx.x * 256 + (int)threadIdx.x;   // 0..24575
    const int kc   = fid / 768;
    const int rem  = fid - kc * 768;
    const int sub  = rem >> 6;
    const int lane = rem & 63;
    const int row  = (sub & 3) * 16 + (lane & 15);
    const int e0   = kc * 32 + (lane >> 4) * 8;
    const float* W = (sub < 4) ? Wq : ((sub < 8) ? Wk : Wv);
    const float4 a0 = *(const float4*)(W + (size_t)row * EMB + e0);
    const float4 a1 = *(const float4*)(W + (size_t)row * EMB + e0 + 4);
    bf16x8 w;
    w[0] = (short)f2bf(a0.x); w[1] = (short)f2bf(a0.y);
    w[2] = (short)f2bf(a0.z); w[3] = (short)f2bf(a0.w);
    w[4] = (short)f2bf(a1.x); w[5] = (short)f2bf(a1.y);
    w[6] = (short)f2bf(a1.z); w[7] = (short)f2bf(a1.w);
    *(bf16x8*)(Wf + (size_t)fid * 8) = w;
    if (blockIdx.x == 0 && threadIdx.x < 192) {
        const int i = (int)threadIdx.x;
        const float* B = (i < 64) ? bq : ((i < 128) ? bk : bv);
        bb[i] = B[i & 63];
    }
    if (blockIdx.x == 1 && threadIdx.x < 128) cnt[threadIdx.x] = 0u;
}

// ---- QKV GEMM v2: 32 rows/block, 8 waves = (sub-triple sg) x (kc-parity kp)
// Each Wf fragment feeds TWO MFMAs (row-groups 0/1). K-halved staging: half-1
// x loads issued after barrier 1, fly under phase-0 compute. kc-parity
// partials reduced via LDS; kp==0 waves do the epilogue.
__global__ __launch_bounds__(512, 2) void qkv_gemm(
    const float* __restrict__ x, const ushort* __restrict__ Wf,
    const float* __restrict__ bb,
    ushort* __restrict__ Qf, ushort* __restrict__ Kf, ushort* __restrict__ Vf)
{
    const int t0   = (int)blockIdx.x * 32;
    const int tid  = (int)threadIdx.x;
    const int wv   = tid >> 6;
    const int lane = tid & 63;
    const int col  = lane & 15, quad = lane >> 4;
    const int sg   = wv >> 1;            // sub-triple 0..3
    const int kp   = wv & 1;             // kc parity
    const int sub0 = sg * 3;

    __shared__ ushort xs[32][XS_STRIDE];              // 66.6 KB
    __shared__ __align__(16) float red[4][64][24];    // 24.6 KB

    // ---- stage half 0 (cols 0..511): 32 rows x 512 fp32 -> bf16, coalesced
    float4 v0[8];
    #pragma unroll
    for (int i = 0; i < 8; ++i) {
        const int idx = i * 512 + tid;
        const int row = idx >> 7, c4 = idx & 127;
        v0[i] = *(const float4*)(x + (size_t)(t0 + row) * EMB + c4 * 4);
    }
    #pragma unroll
    for (int i = 0; i < 8; ++i) {
        const int idx = i * 512 + tid;
        const int row = idx >> 7, c4 = idx & 127;
        ushort4 pk;
        pk.x = f2bf(v0[i].x); pk.y = f2bf(v0[i].y);
        pk.z = f2bf(v0[i].z); pk.w = f2bf(v0[i].w);
        *(ushort4*)&xs[row][c4 * 4] = pk;
    }
    __syncthreads();

    // ---- issue half-1 loads now: they complete under phase-0 compute
    float4 v1[8];
    #pragma unroll
    for (int i = 0; i < 8; ++i) {
        const int idx = i * 512 + tid;
        const int row = idx >> 7, c4 = idx & 127;
        v1[i] = *(const float4*)(x + (size_t)(t0 + row) * EMB + 512 + c4 * 4);
    }

    f32x4 acc[2][3];
    #pragma unroll
    for (int rg = 0; rg < 2; ++rg)
        #pragma unroll
        for (int s = 0; s < 3; ++s) acc[rg][s] = (f32x4){0.f, 0.f, 0.f, 0.f};

    // ---- phase 0: kc = kp + 2t (all < 16, reads cols < 512 only)
    #pragma unroll 4
    for (int t = 0; t < 8; ++t) {
        const int kc = kp + 2 * t;
        const bf16x8 a0 = *(const bf16x8*)&xs[col][kc * 32 + quad * 8];
        const bf16x8 a1 = *(const bf16x8*)&xs[16 + col][kc * 32 + quad * 8];
        #pragma unroll
        for (int s = 0; s < 3; ++s) {
            const bf16x8 w = *(const bf16x8*)(Wf + ((size_t)(kc * 12 + sub0 + s) * 64 + lane) * 8);
            acc[0][s] = __builtin_amdgcn_mfma_f32_16x16x32_bf16(a0, w, acc[0][s], 0, 0, 0);
            acc[1][s] = __builtin_amdgcn_mfma_f32_16x16x32_bf16(a1, w, acc[1][s], 0, 0, 0);
        }
    }

    // ---- write half 1 (cols 512..1023: disjoint from phase-0 reads, no race)
    #pragma unroll
    for (int i = 0; i < 8; ++i) {
        const int idx = i * 512 + tid;
        const int row = idx >> 7, c4 = idx & 127;
        ushort4 pk;
        pk.x = f2bf(v1[i].x); pk.y = f2bf(v1[i].y);
        pk.z = f2bf(v1[i].z); pk.w = f2bf(v1[i].w);
        *(ushort4*)&xs[row][512 + c4 * 4] = pk;
    }
    __syncthreads();

    // ---- phase 1: kc = 16 + kp + 2t
    #pragma unroll 4
    for (int t = 0; t < 8; ++t) {
        const int kc = 16 + kp + 2 * t;
        const bf16x8 a0 = *(const bf16x8*)&xs[col][kc * 32 + quad * 8];
        const bf16x8 a1 = *(const bf16x8*)&xs[16 + col][kc * 32 + quad * 8];
        #pragma unroll
        for (int s = 0; s < 3; ++s) {
            const bf16x8 w = *(const bf16x8*)(Wf + ((size_t)(kc * 12 + sub0 + s) * 64 + lane) * 8);
            acc[0][s] = __builtin_amdgcn_mfma_f32_16x16x32_bf16(a0, w, acc[0][s], 0, 0, 0);
            acc[1][s] = __builtin_amdgcn_mfma_f32_16x16x32_bf16(a1, w, acc[1][s], 0, 0, 0);
        }
    }

    // ---- kc-parity reduce: kp=1 waves publish, kp=0 waves sum + epilogue
    if (kp) {
        #pragma unroll
        for (int rg = 0; rg < 2; ++rg)
            #pragma unroll
            for (int s = 0; s < 3; ++s)
                *(f32x4*)&red[sg][lane][(rg * 3 + s) * 4] = acc[rg][s];
    }
    __syncthreads();
    if (kp) return;
    #pragma unroll
    for (int rg = 0; rg < 2; ++rg)
        #pragma unroll
        for (int s = 0; s < 3; ++s)
            acc[rg][s] += *(const f32x4*)&red[sg][lane][(rg * 3 + s) * 4];

    // ---- epilogue: bias + write in fragment order, two 16-row groups
    #pragma unroll
    for (int rg = 0; rg < 2; ++rg) {
        const int tt0 = t0 + rg * 16;
        const int b   = tt0 >> 11;
        const int qt  = (tt0 >> 4) & 127;
        const int sgt = tt0 + quad * 4;               // first of 4 consecutive t/s
        const int itk = (sgt & (SEQ - 1)) >> 6;       // batch-LOCAL K-tile
        #pragma unroll
        for (int s = 0; s < 3; ++s) {
            const int sub  = sub0 + s;
            const int hrow = sub * 16 + col;
            const float bias = bb[hrow];
            if (sub < 4) {                            // Q (scaled)
                const int h = hrow;
                const int f = h >> 5, qd = (h >> 3) & 3, jj = h & 7;
                ushort* base = Qf + (((size_t)(b * 128 + qt) * 2 + f) * 64 + qd * 16 + quad * 4) * 8 + jj;
                #pragma unroll
                for (int i = 0; i < 4; ++i)
                    base[i * 8] = f2bf((acc[rg][s][i] + bias) * QSCALE);
            } else if (sub < 8) {                     // K
                const int h = hrow - 64;
                const int f = h >> 5, qd = (h >> 3) & 3, jj = h & 7;
                const size_t frag = ((size_t)(b * 32 + itk) * 4 + ((sgt >> 4) & 3)) * 2 + f;
                ushort* base = Kf + frag * 512 + ((size_t)((sgt & 15) + 16 * qd)) * 8 + jj;
                #pragma unroll
                for (int i = 0; i < 4; ++i)
                    base[i * 8] = f2bf(acc[rg][s][i] + bias);
            } else {                                  // V (B-frag of PV: n=h, k=s)
                const int h = hrow - 128;
                const int k0 = sgt & 63;
                const int f = k0 >> 5, qd = (k0 >> 3) & 3, j0 = k0 & 7;
                const size_t frag = ((size_t)(b * 32 + itk) * 4 + (h >> 4)) * 2 + f;
                ushort4 pk;
                pk.x = f2bf(acc[rg][s][0] + bias); pk.y = f2bf(acc[rg][s][1] + bias);
                pk.z = f2bf(acc[rg][s][2] + bias); pk.w = f2bf(acc[rg][s][3] + bias);
                *(ushort4*)(Vf + frag * 512 + ((size_t)((h & 15) + 16 * qd)) * 8 + j0) = pk;
            }
        }
    }
}

// ---- attention v3: 64 Q rows per block, 320 fixed-size work-units ----------
// Unit = (batch b, 64-row q-tile tl, chunk of <=8 K-tiles); one K-tile per
// wave, 64-row Q amortization (total K/V traffic 67.5 -> 33.8 MB) and
// near-perfect CU balance (biggest units dispatched first). Multi-chunk
// tiles merge via global partials + per-tile arrival counter: the last block
// to arrive sums and normalizes (no extra kernel). Single-chunk tiles write
// out directly. LDS: P-transpose and O-merge buffers unioned (139 KB).
__global__ __launch_bounds__(512, 2) void attn(
    const ushort* __restrict__ Qf, const ushort* __restrict__ Kf,
    const ushort* __restrict__ Vf, float* __restrict__ part,
    uint* __restrict__ cnt, float* __restrict__ out)
{
    const int u = (int)blockIdx.x;                    // 0..319
    int b, tl, chunk, chunks;
    if (u < 128)      { const int q = u >> 2;                   b = q >> 3; tl = 24 + (q & 7); chunk = u & 3;     chunks = 4; }
    else if (u < 224) { const int v = u - 128; const int q = v / 3; b = q >> 3; tl = 16 + (q & 7); chunk = v - q * 3; chunks = 3; }
    else if (u < 288) { const int v = u - 224; const int q = v >> 1; b = q >> 3; tl = 8 + (q & 7);  chunk = v & 1;     chunks = 2; }
    else              { const int v = u - 288;                  b = v >> 3; tl = v & 7;        chunk = 0;         chunks = 1; }

    const int t0   = tl * 64;
    const int nt   = tl + 1;                          // K-tiles of 64 covering s<=t0+63
    const int tid  = (int)threadIdx.x;
    const int j    = tid >> 6;                        // wave index (owns one K-tile)
    const int lane = tid & 63;
    const int col  = lane & 15, quad = lane >> 4;
    const int it   = chunk * 8 + j;                   // this wave's K-tile
    const bool active = (it < nt);

    __shared__ __align__(16) char smem[139264];       // union: pt (82K) / op (136K)
    ushort (*pt)[64][80] = (ushort (*)[64][80])smem;  // [8][64][80]
    float  (*op)[64][68] = (float  (*)[64][68])smem;  // [8][64][68]
    __shared__ float ll[8][64];
    __shared__ int flag;

    f32x4 o[4][4];                                    // [q-subtile][dim-group]
    float l_r[16];                                    // per-lane l partials
    #pragma unroll
    for (int qs = 0; qs < 4; ++qs)
        #pragma unroll
        for (int d = 0; d < 4; ++d) o[qs][d] = (f32x4){0.f, 0.f, 0.f, 0.f};
    #pragma unroll
    for (int k = 0; k < 16; ++k) l_r[k] = 0.f;

    if (active) {
        // ---- load Q (4 sub-tiles), K, V fragments for this wave's K-tile
        const ushort* Qb = Qf + ((size_t)(b * 128 + tl * 4) * 2) * 512;
        bf16x8 aq[4][2];
        #pragma unroll
        for (int qs = 0; qs < 4; ++qs) {
            aq[qs][0] = *(const bf16x8*)(Qb + (size_t)(qs * 2 + 0) * 512 + (size_t)lane * 8);
            aq[qs][1] = *(const bf16x8*)(Qb + (size_t)(qs * 2 + 1) * 512 + (size_t)lane * 8);
        }
        const ushort* Kt = Kf + ((size_t)(b * 32 + it) * 8) * 512;
        bf16x8 kc[4][2];
        #pragma unroll
        for (int sub = 0; sub < 4; ++sub) {
            kc[sub][0] = *(const bf16x8*)(Kt + (size_t)(sub * 2 + 0) * 512 + (size_t)lane * 8);
            kc[sub][1] = *(const bf16x8*)(Kt + (size_t)(sub * 2 + 1) * 512 + (size_t)lane * 8);
        }
        const ushort* Vt = Vf + ((size_t)(b * 32 + it) * 8) * 512;
        bf16x8 vf[4][2];
        #pragma unroll
        for (int sub = 0; sub < 4; ++sub) {
            vf[sub][0] = *(const bf16x8*)(Vt + (size_t)(sub * 2 + 0) * 512 + (size_t)lane * 8);
            vf[sub][1] = *(const bf16x8*)(Vt + (size_t)(sub * 2 + 1) * 512 + (size_t)lane * 8);
        }

        const int s0 = it * 64;
        const bool diag = (it == nt - 1);

        // ---- QK^T + no-max softmax, one 16-row q-subtile at a time
        #pragma unroll
        for (int qs = 0; qs < 4; ++qs) {
            f32x4 sc[4];
            #pragma unroll
            for (int sub = 0; sub < 4; ++sub) {
                f32x4 z = {0.f, 0.f, 0.f, 0.f};
                z = __builtin_amdgcn_mfma_f32_16x16x32_bf16(aq[qs][0], kc[sub][0], z, 0, 0, 0);
                z = __builtin_amdgcn_mfma_f32_16x16x32_bf16(aq[qs][1], kc[sub][1], z, 0, 0, 0);
                sc[sub] = z;
            }
            if (diag) {
                #pragma unroll
                for (int sub = 0; sub < 4; ++sub)
                    #pragma unroll
                    for (int i = 0; i < 4; ++i) {
                        const int s = s0 + sub * 16 + col;
                        const int t = t0 + qs * 16 + quad * 4 + i;
                        if (s > t) sc[sub][i] = -1e30f;   // exp2 -> 0
                    }
            }
            #pragma unroll
            for (int sub = 0; sub < 4; ++sub)
                #pragma unroll
                for (int i = 0; i < 4; ++i) {
                    const float p = exp2f(sc[sub][i]);
                    l_r[qs * 4 + i] += p;
                    pt[j][qs * 16 + quad * 4 + i][sub * 16 + col] = f2bf(p);
                }
        }

        // ---- P: C/D -> A-operand via LDS (same-wave: waitcnt only)
        __asm__ volatile("s_waitcnt lgkmcnt(0)" ::: "memory");
        #pragma unroll
        for (int qs = 0; qs < 4; ++qs) {
            const bf16x8 ap0 = *(const bf16x8*)&pt[j][qs * 16 + col][quad * 8];
            const bf16x8 ap1 = *(const bf16x8*)&pt[j][qs * 16 + col][32 + quad * 8];
            #pragma unroll
            for (int d = 0; d < 4; ++d) {
                o[qs][d] = __builtin_amdgcn_mfma_f32_16x16x32_bf16(ap0, vf[d][0], o[qs][d], 0, 0, 0);
                o[qs][d] = __builtin_amdgcn_mfma_f32_16x16x32_bf16(ap1, vf[d][1], o[qs][d], 0, 0, 0);
            }
        }
    }

    // ---- butterfly for l (sum over the 16 col lanes of each row group)
    #pragma unroll
    for (int d = 1; d < 16; d <<= 1)
        #pragma unroll
        for (int k = 0; k < 16; ++k) l_r[k] += __shfl_xor(l_r[k], d, 64);

    __syncthreads();                                  // all pt reads done before op overwrite

    // ---- publish per-wave partial (inactive waves publish zeros)
    #pragma unroll
    for (int qs = 0; qs < 4; ++qs)
        #pragma unroll
        for (int d = 0; d < 4; ++d)
            #pragma unroll
            for (int i = 0; i < 4; ++i)
                op[j][qs * 16 + quad * 4 + i][d * 16 + col] = o[qs][d][i];
    if (col == 0) {
        #pragma unroll
        for (int qs = 0; qs < 4; ++qs)
            #pragma unroll
            for (int i = 0; i < 4; ++i)
                ll[j][qs * 16 + quad * 4 + i] = l_r[qs * 4 + i];
    }
    __syncthreads();

    // ---- merge 8 wave-partials: thread = (row 0..63, 8-col group)
    const int row = tid >> 3, c0 = (tid & 7) * 8;
    float acc[8];
    #pragma unroll
    for (int c = 0; c < 8; ++c) acc[c] = 0.f;
    float ls = 0.f;
    #pragma unroll
    for (int w = 0; w < 8; ++w) {
        #pragma unroll
        for (int c = 0; c < 8; ++c) acc[c] += op[w][row][c0 + c];
        ls += ll[w][row];
    }

    if (chunks == 1) {
        const float rinv = 1.0f / ls;
        float4 r0, r1;
        r0.x = acc[0] * rinv; r0.y = acc[1] * rinv; r0.z = acc[2] * rinv; r0.w = acc[3] * rinv;
        r1.x = acc[4] * rinv; r1.y = acc[5] * rinv; r1.z = acc[6] * rinv; r1.w = acc[7] * rinv;
        float* dst = out + ((size_t)b * SEQ + t0 + row) * HD + c0;
        *(float4*)dst = r0; *(float4*)(dst + 4) = r1;
    } else {
        // ---- write unnormalized partial + l to this unit's slot
        float* slot = part + (size_t)u * 4160;
        *(float4*)(slot + row * 64 + c0)     = (float4){acc[0], acc[1], acc[2], acc[3]};
        *(float4*)(slot + row * 64 + c0 + 4) = (float4){acc[4], acc[5], acc[6], acc[7]};
        if ((tid & 7) == 0) slot[4096 + row] = ls;
        __threadfence();
        __syncthreads();
        if (tid == 0) flag = (int)atomicAdd(&cnt[b * 32 + tl], 1u);
        __syncthreads();
        if (flag == chunks - 1) {                     // last arriver merges
            __threadfence();
            int base;
            if (tl >= 24)      base = 4 * ((b << 3) + (tl - 24));
            else if (tl >= 16) base = 128 + 3 * ((b << 3) + (tl - 16));
            else               base = 224 + 2 * ((b << 3) + (tl - 8));
            float fa[8];
            #pragma unroll
            for (int c = 0; c < 8; ++c) fa[c] = 0.f;
            float fls = 0.f;
            for (int cc = 0; cc < chunks; ++cc) {
                const float* s2 = part + (size_t)(base + cc) * 4160;
                const float4 p0 = *(const float4*)(s2 + row * 64 + c0);
                const float4 p1 = *(const float4*)(s2 + row * 64 + c0 + 4);
                fa[0] += p0.x; fa[1] += p0.y; fa[2] += p0.z; fa[3] += p0.w;
                fa[4] += p1.x; fa[5] += p1.y; fa[6] += p1.z; fa[7] += p1.w;
                fls += s2[4096 + row];
            }
            const float rinv = 1.0f / fls;
            float4 r0, r1;
            r0.x = fa[0] * rinv; r0.y = fa[1] * rinv; r0.z = fa[2] * rinv; r0.w = fa[3] * rinv;
            r1.x = fa[4] * rinv; r1.y = fa[5] * rinv; r1.z = fa[6] * rinv; r1.w = fa[7] * rinv;
            float* dst = out + ((size_t)b * SEQ + t0 + row) * HD + c0;
            *(float4*)dst = r0; *(float4*)(dst + 4) = r1;
        }
    }
}

extern "C" void kernel_launch(void* const* d_in, const int* in_sizes, int n_in,
                              void* d_out, int out_size, void* d_ws, size_t ws_size,
                              hipStream_t stream)
{
    const float* x  = (const float*)d_in[0];
    const float* Wq = (const float*)d_in[1];
    const float* bq = (const float*)d_in[2];
    const float* Wk = (const float*)d_in[3];
    const float* bk = (const float*)d_in[4];
    const float* Wv = (const float*)d_in[5];
    const float* bv = (const float*)d_in[6];
    float* out = (float*)d_out;

    char* ws = (char*)d_ws;
    ushort* Wf   = (ushort*)(ws);                       // 384 KB
    float*  bb   = (float*)(ws + 0x60000);              // 768 B
    uint*   cnt  = (uint*)(ws + 0x60400);               // 512 B (128 tiles)
    ushort* Qfb  = (ushort*)(ws + 0x61000);             // 1 MB
    ushort* Kfb  = (ushort*)(ws + 0x161000);            // 1 MB
    ushort* Vfb  = (ushort*)(ws + 0x261000);            // 1 MB
    float*  part = (float*)(ws + 0x361000);             // 320 * 16640 B ~ 5.1 MB

    prep<<<96, 256, 0, stream>>>(Wq, bq, Wk, bk, Wv, bv, Wf, bb, cnt);
    qkv_gemm<<<BT / 32, 512, 0, stream>>>(x, Wf, bb, Qfb, Kfb, Vfb);
    attn<<<320, 512, 0, stream>>>(Qfb, Kfb, Vfb, part, cnt, out);
}

// Round 3
// 111.023 us; speedup vs baseline: 1.8756x; 1.8756x over previous
//
#include <hip/hip_runtime.h>
#include <hip/hip_bf16.h>

#define BATCH 4
#define SEQ   2048
#define EMB   1024
#define HD    64
#define BT    (BATCH * SEQ)
#define XS_STRIDE 1040   // dword stride 520 = 8 mod 32

// logits scale 1/sqrt(64) folded with log2(e) so softmax can use exp2 directly
#define QSCALE 0.18033688011112042f

typedef __attribute__((ext_vector_type(8))) short bf16x8;
typedef __attribute__((ext_vector_type(4))) float f32x4;

__device__ __forceinline__ ushort f2bf(float f) {   // RTN fp32 -> bf16 bits
    unsigned u = __float_as_uint(f);
    return (ushort)((u + 0x7FFFu + ((u >> 16) & 1u)) >> 16);
}

// ---- prep: Wf = W in MFMA B-fragment order [kc(32)][sub(12)][lane(64)][8] --
// frag element (lane,j): row = sub*16 + (lane&15), e = kc*32 + (lane>>4)*8 + j
__global__ __launch_bounds__(256) void prep(
    const float* __restrict__ Wq, const float* __restrict__ bq,
    const float* __restrict__ Wk, const float* __restrict__ bk,
    const float* __restrict__ Wv, const float* __restrict__ bv,
    ushort* __restrict__ Wf, float* __restrict__ bb)
{
    const int fid = (int)blockIdx.x * 256 + (int)threadIdx.x;   // 0..24575
    const int kc   = fid / 768;
    const int rem  = fid - kc * 768;
    const int sub  = rem >> 6;
    const int lane = rem & 63;
    const int row  = (sub & 3) * 16 + (lane & 15);
    const int e0   = kc * 32 + (lane >> 4) * 8;
    const float* W = (sub < 4) ? Wq : ((sub < 8) ? Wk : Wv);
    const float4 a0 = *(const float4*)(W + (size_t)row * EMB + e0);
    const float4 a1 = *(const float4*)(W + (size_t)row * EMB + e0 + 4);
    bf16x8 w;
    w[0] = (short)f2bf(a0.x); w[1] = (short)f2bf(a0.y);
    w[2] = (short)f2bf(a0.z); w[3] = (short)f2bf(a0.w);
    w[4] = (short)f2bf(a1.x); w[5] = (short)f2bf(a1.y);
    w[6] = (short)f2bf(a1.z); w[7] = (short)f2bf(a1.w);
    *(bf16x8*)(Wf + (size_t)fid * 8) = w;
    if (blockIdx.x == 0 && threadIdx.x < 192) {
        const int i = (int)threadIdx.x;
        const float* B = (i < 64) ? bq : ((i < 128) ? bk : bv);
        bb[i] = B[i & 63];
    }
}

// ---- QKV GEMM v3: 32 rows/block, 8 waves = (sub-triple sg) x (row-group rg)
// Each wave owns a COMPLETE K-reduction for its 3 subs x 16 rows: no parity
// reduce, no red LDS, no extra barrier. Wf fragments still amortized over 32
// rows per block (rg-pair waves read identical lines -> L1/L2 dedup).
// K-halved staging: half-1 x loads issued after barrier 1, fly under phase-0
// compute. LDS = 66.6 KB.
__global__ __launch_bounds__(512, 2) void qkv_gemm(
    const float* __restrict__ x, const ushort* __restrict__ Wf,
    const float* __restrict__ bb,
    ushort* __restrict__ Qf, ushort* __restrict__ Kf, ushort* __restrict__ Vf)
{
    const int t0   = (int)blockIdx.x * 32;
    const int tid  = (int)threadIdx.x;
    const int wv   = tid >> 6;
    const int lane = tid & 63;
    const int col  = lane & 15, quad = lane >> 4;
    const int sg   = wv >> 1;            // sub-triple 0..3
    const int rg   = wv & 1;             // row-group 0..1
    const int sub0 = sg * 3;
    const int arow = rg * 16 + col;      // this wave's A-fragment row

    __shared__ ushort xs[32][XS_STRIDE];              // 66.6 KB

    // ---- stage half 0 (cols 0..511): 32 rows x 512 fp32 -> bf16, coalesced
    float4 v0[8];
    #pragma unroll
    for (int i = 0; i < 8; ++i) {
        const int idx = i * 512 + tid;
        const int row = idx >> 7, c4 = idx & 127;
        v0[i] = *(const float4*)(x + (size_t)(t0 + row) * EMB + c4 * 4);
    }
    #pragma unroll
    for (int i = 0; i < 8; ++i) {
        const int idx = i * 512 + tid;
        const int row = idx >> 7, c4 = idx & 127;
        ushort4 pk;
        pk.x = f2bf(v0[i].x); pk.y = f2bf(v0[i].y);
        pk.z = f2bf(v0[i].z); pk.w = f2bf(v0[i].w);
        *(ushort4*)&xs[row][c4 * 4] = pk;
    }
    __syncthreads();

    // ---- issue half-1 loads now: they complete under phase-0 compute
    float4 v1[8];
    #pragma unroll
    for (int i = 0; i < 8; ++i) {
        const int idx = i * 512 + tid;
        const int row = idx >> 7, c4 = idx & 127;
        v1[i] = *(const float4*)(x + (size_t)(t0 + row) * EMB + 512 + c4 * 4);
    }

    f32x4 acc[3];
    #pragma unroll
    for (int s = 0; s < 3; ++s) acc[s] = (f32x4){0.f, 0.f, 0.f, 0.f};

    // ---- phase 0: kc = 0..15 (reads cols < 512 only)
    #pragma unroll 4
    for (int kc = 0; kc < 16; ++kc) {
        const bf16x8 a = *(const bf16x8*)&xs[arow][kc * 32 + quad * 8];
        #pragma unroll
        for (int s = 0; s < 3; ++s) {
            const bf16x8 w = *(const bf16x8*)(Wf + ((size_t)(kc * 12 + sub0 + s) * 64 + lane) * 8);
            acc[s] = __builtin_amdgcn_mfma_f32_16x16x32_bf16(a, w, acc[s], 0, 0, 0);
        }
    }

    // ---- write half 1 (cols 512..1023: disjoint from phase-0 reads, no race)
    #pragma unroll
    for (int i = 0; i < 8; ++i) {
        const int idx = i * 512 + tid;
        const int row = idx >> 7, c4 = idx & 127;
        ushort4 pk;
        pk.x = f2bf(v1[i].x); pk.y = f2bf(v1[i].y);
        pk.z = f2bf(v1[i].z); pk.w = f2bf(v1[i].w);
        *(ushort4*)&xs[row][512 + c4 * 4] = pk;
    }
    __syncthreads();

    // ---- phase 1: kc = 16..31
    #pragma unroll 4
    for (int kc = 16; kc < 32; ++kc) {
        const bf16x8 a = *(const bf16x8*)&xs[arow][kc * 32 + quad * 8];
        #pragma unroll
        for (int s = 0; s < 3; ++s) {
            const bf16x8 w = *(const bf16x8*)(Wf + ((size_t)(kc * 12 + sub0 + s) * 64 + lane) * 8);
            acc[s] = __builtin_amdgcn_mfma_f32_16x16x32_bf16(a, w, acc[s], 0, 0, 0);
        }
    }

    // ---- epilogue: bias + write in fragment order (this wave's row-group)
    {
        const int tt0 = t0 + rg * 16;
        const int b   = tt0 >> 11;
        const int qt  = (tt0 >> 4) & 127;
        const int sgt = tt0 + quad * 4;               // first of 4 consecutive t/s
        const int itk = (sgt & (SEQ - 1)) >> 6;       // batch-LOCAL K-tile
        #pragma unroll
        for (int s = 0; s < 3; ++s) {
            const int sub  = sub0 + s;
            const int hrow = sub * 16 + col;
            const float bias = bb[hrow];
            if (sub < 4) {                            // Q (scaled)
                const int h = hrow;
                const int f = h >> 5, qd = (h >> 3) & 3, jj = h & 7;
                ushort* base = Qf + (((size_t)(b * 128 + qt) * 2 + f) * 64 + qd * 16 + quad * 4) * 8 + jj;
                #pragma unroll
                for (int i = 0; i < 4; ++i)
                    base[i * 8] = f2bf((acc[s][i] + bias) * QSCALE);
            } else if (sub < 8) {                     // K
                const int h = hrow - 64;
                const int f = h >> 5, qd = (h >> 3) & 3, jj = h & 7;
                const size_t frag = ((size_t)(b * 32 + itk) * 4 + ((sgt >> 4) & 3)) * 2 + f;
                ushort* base = Kf + frag * 512 + ((size_t)((sgt & 15) + 16 * qd)) * 8 + jj;
                #pragma unroll
                for (int i = 0; i < 4; ++i)
                    base[i * 8] = f2bf(acc[s][i] + bias);
            } else {                                  // V (B-frag of PV: n=h, k=s)
                const int h = hrow - 128;
                const int k0 = sgt & 63;
                const int f = k0 >> 5, qd = (k0 >> 3) & 3, j0 = k0 & 7;
                const size_t frag = ((size_t)(b * 32 + itk) * 4 + (h >> 4)) * 2 + f;
                ushort4 pk;
                pk.x = f2bf(acc[s][0] + bias); pk.y = f2bf(acc[s][1] + bias);
                pk.z = f2bf(acc[s][2] + bias); pk.w = f2bf(acc[s][3] + bias);
                *(ushort4*)(Vf + frag * 512 + ((size_t)((h & 15) + 16 * qd)) * 8 + j0) = pk;
            }
        }
    }
}

// ---- attention (round-1 proven version): 256 blocks x 8 waves, 32 Q rows --
// Each K/V fragment load feeds 32 MFMAs (2 Q tiles). 8-way K split; looped
// K-tiles with K-prefetch rotation keep registers bounded and latency hidden.
// In-block LDS merge of 8 partials. LDS = 40K (pt) + 68K (op) + 1K (ll).
__global__ __launch_bounds__(512, 2) void attn(
    const ushort* __restrict__ Qf, const ushort* __restrict__ Kf,
    const ushort* __restrict__ Vf, float* __restrict__ out)
{
    const int blk  = (int)blockIdx.x;                 // 0..255
    const int b    = blk & 3;
    const int tl   = 63 - (blk >> 2);                 // longest tiles first
    const int t0   = tl * 32;
    const int nt   = ((t0 + 31) >> 6) + 1;            // K-tiles of 64 covering s<=t0+31
    const int tid  = (int)threadIdx.x;
    const int j    = tid >> 6;                        // wave = split index (0..7)
    const int lane = tid & 63;
    const int col  = lane & 15, quad = lane >> 4;

    const ushort* QbA = Qf + ((size_t)(b * 128 + 2 * tl) * 2) * 512;
    const bf16x8 aqA0 = *(const bf16x8*)(QbA + (size_t)lane * 8);
    const bf16x8 aqA1 = *(const bf16x8*)(QbA + 512 + (size_t)lane * 8);
    const bf16x8 aqB0 = *(const bf16x8*)(QbA + 1024 + (size_t)lane * 8);
    const bf16x8 aqB1 = *(const bf16x8*)(QbA + 1536 + (size_t)lane * 8);

    float l_a[4], l_b[4];                             // per-LANE partial sums
    f32x4 o[8];                                       // [0..3]=tileA, [4..7]=tileB
    #pragma unroll
    for (int i = 0; i < 4; ++i) { l_a[i] = 0.f; l_b[i] = 0.f; }
    #pragma unroll
    for (int i = 0; i < 8; ++i) o[i] = (f32x4){0.f, 0.f, 0.f, 0.f};

    __shared__ ushort pt[8][32][80];                  // per-wave P transpose tile
    __shared__ __align__(16) float op[8][32][68];     // per-wave O partial
    __shared__ float ll[8][32];

    // prologue: K fragments for first tile (only if this wave has work)
    bf16x8 kc[4][2];
    if (j < nt) {
        const ushort* Kt = Kf + ((size_t)(b * 32 + j) * 8) * 512;
        #pragma unroll
        for (int sub = 0; sub < 4; ++sub) {
            kc[sub][0] = *(const bf16x8*)(Kt + (size_t)(sub * 2 + 0) * 512 + (size_t)lane * 8);
            kc[sub][1] = *(const bf16x8*)(Kt + (size_t)(sub * 2 + 1) * 512 + (size_t)lane * 8);
        }
    }

    for (int it = j; it < nt; it += 8) {
        const int s0 = it * 64;
        const bool hasNext = (it + 8 < nt);

        // ---- S = (q*scale) . k^T for both Q tiles from current K fragments
        f32x4 scA[4], scB[4];
        #pragma unroll
        for (int sub = 0; sub < 4; ++sub) {
            f32x4 z = {0.f, 0.f, 0.f, 0.f};
            z = __builtin_amdgcn_mfma_f32_16x16x32_bf16(aqA0, kc[sub][0], z, 0, 0, 0);
            z = __builtin_amdgcn_mfma_f32_16x16x32_bf16(aqA1, kc[sub][1], z, 0, 0, 0);
            scA[sub] = z;
            f32x4 y = {0.f, 0.f, 0.f, 0.f};
            y = __builtin_amdgcn_mfma_f32_16x16x32_bf16(aqB0, kc[sub][0], y, 0, 0, 0);
            y = __builtin_amdgcn_mfma_f32_16x16x32_bf16(aqB1, kc[sub][1], y, 0, 0, 0);
            scB[sub] = y;
        }

        // ---- issue V(cur), then K(next) only if a next iter exists
        bf16x8 kn[4][2], vf[4][2];
        {
            const ushort* Vt = Vf + ((size_t)(b * 32 + it) * 8) * 512;
            #pragma unroll
            for (int sub = 0; sub < 4; ++sub) {
                vf[sub][0] = *(const bf16x8*)(Vt + (size_t)(sub * 2 + 0) * 512 + (size_t)lane * 8);
                vf[sub][1] = *(const bf16x8*)(Vt + (size_t)(sub * 2 + 1) * 512 + (size_t)lane * 8);
            }
        }
        if (hasNext) {
            const ushort* Kt = Kf + ((size_t)(b * 32 + it + 8) * 8) * 512;
            #pragma unroll
            for (int sub = 0; sub < 4; ++sub) {
                kn[sub][0] = *(const bf16x8*)(Kt + (size_t)(sub * 2 + 0) * 512 + (size_t)lane * 8);
                kn[sub][1] = *(const bf16x8*)(Kt + (size_t)(sub * 2 + 1) * 512 + (size_t)lane * 8);
            }
        }

        if (it == nt - 1) {                           // only the diagonal tile masks
            #pragma unroll
            for (int sub = 0; sub < 4; ++sub)
                #pragma unroll
                for (int i = 0; i < 4; ++i) {
                    const int s  = s0 + sub * 16 + col;
                    const int tA = t0 + quad * 4 + i;
                    if (s > tA)      scA[sub][i] = -1e30f;   // exp2 -> 0
                    if (s > tA + 16) scB[sub][i] = -1e30f;
                }
        }

        // ---- p = exp2(sc); accumulate l per-lane; stage P for transpose
        #pragma unroll
        for (int sub = 0; sub < 4; ++sub)
            #pragma unroll
            for (int i = 0; i < 4; ++i) {
                const float pA = exp2f(scA[sub][i]);
                l_a[i] += pA;
                pt[j][quad * 4 + i][sub * 16 + col] = f2bf(pA);
                const float pB = exp2f(scB[sub][i]);
                l_b[i] += pB;
                pt[j][16 + quad * 4 + i][sub * 16 + col] = f2bf(pB);
            }

        // ---- P: C/D -> A-operand via LDS (same-wave: waitcnt only, no barrier)
        __asm__ volatile("s_waitcnt lgkmcnt(0)" ::: "memory");
        const bf16x8 apA0 = *(const bf16x8*)&pt[j][col][quad * 8];
        const bf16x8 apA1 = *(const bf16x8*)&pt[j][col][32 + quad * 8];
        const bf16x8 apB0 = *(const bf16x8*)&pt[j][16 + col][quad * 8];
        const bf16x8 apB1 = *(const bf16x8*)&pt[j][16 + col][32 + quad * 8];

        // ---- O += P @ V from prefetched V fragments (shared by both tiles)
        #pragma unroll
        for (int sub = 0; sub < 4; ++sub) {
            o[sub]     = __builtin_amdgcn_mfma_f32_16x16x32_bf16(apA0, vf[sub][0], o[sub], 0, 0, 0);
            o[sub]     = __builtin_amdgcn_mfma_f32_16x16x32_bf16(apA1, vf[sub][1], o[sub], 0, 0, 0);
            o[4 + sub] = __builtin_amdgcn_mfma_f32_16x16x32_bf16(apB0, vf[sub][0], o[4 + sub], 0, 0, 0);
            o[4 + sub] = __builtin_amdgcn_mfma_f32_16x16x32_bf16(apB1, vf[sub][1], o[4 + sub], 0, 0, 0);
        }

        // ---- rotate K
        if (hasNext) {
            #pragma unroll
            for (int sub = 0; sub < 4; ++sub) { kc[sub][0] = kn[sub][0]; kc[sub][1] = kn[sub][1]; }
        }
    }

    // ---- one butterfly for l (sum over the 16 lanes of each quad-row group)
    #pragma unroll
    for (int d = 1; d < 16; d <<= 1)
        #pragma unroll
        for (int i = 0; i < 4; ++i) {
            l_a[i] += __shfl_xor(l_a[i], d, 64);
            l_b[i] += __shfl_xor(l_b[i], d, 64);
        }

    // ---- publish per-wave partial to LDS (waves with no work publish zeros)
    #pragma unroll
    for (int sub = 0; sub < 4; ++sub)
        #pragma unroll
        for (int i = 0; i < 4; ++i) {
            op[j][quad * 4 + i][sub * 16 + col]      = o[sub][i];
            op[j][16 + quad * 4 + i][sub * 16 + col] = o[4 + sub][i];
        }
    if (col == 0) {
        #pragma unroll
        for (int i = 0; i < 4; ++i) {
            ll[j][quad * 4 + i]      = l_a[i];
            ll[j][16 + quad * 4 + i] = l_b[i];
        }
    }
    __syncthreads();

    // ---- merge 8 wave-partials: thread = (row 0..31, 4-col group); direct write
    {
        const int row = tid >> 4, c0 = (tid & 15) * 4;
        float sx = 0.f, sy = 0.f, sz = 0.f, sw = 0.f, ls = 0.f;
        #pragma unroll
        for (int w = 0; w < 8; ++w) {
            const float4 p = *(const float4*)&op[w][row][c0];
            sx += p.x; sy += p.y; sz += p.z; sw += p.w;
            ls += ll[w][row];
        }
        const float rinv = 1.0f / ls;
        float4 res;
        res.x = sx * rinv; res.y = sy * rinv; res.z = sz * rinv; res.w = sw * rinv;
        *(float4*)(out + ((size_t)b * SEQ + t0 + row) * HD + c0) = res;
    }
}

extern "C" void kernel_launch(void* const* d_in, const int* in_sizes, int n_in,
                              void* d_out, int out_size, void* d_ws, size_t ws_size,
                              hipStream_t stream)
{
    const float* x  = (const float*)d_in[0];
    const float* Wq = (const float*)d_in[1];
    const float* bq = (const float*)d_in[2];
    const float* Wk = (const float*)d_in[3];
    const float* bk = (const float*)d_in[4];
    const float* Wv = (const float*)d_in[5];
    const float* bv = (const float*)d_in[6];
    float* out = (float*)d_out;

    char* ws = (char*)d_ws;
    ushort* Wf  = (ushort*)(ws);                        // 384 KB
    float*  bb  = (float*)(ws + 0x60000);               // 768 B
    ushort* Qfb = (ushort*)(ws + 0x61000);              // 1 MB
    ushort* Kfb = (ushort*)(ws + 0x161000);             // 1 MB
    ushort* Vfb = (ushort*)(ws + 0x261000);             // 1 MB

    prep<<<96, 256, 0, stream>>>(Wq, bq, Wk, bk, Wv, bv, Wf, bb);
    qkv_gemm<<<BT / 32, 512, 0, stream>>>(x, Wf, bb, Qfb, Kfb, Vfb);
    attn<<<256, 512, 0, stream>>>(Qfb, Kfb, Vfb, out);
}

// Round 4
// 105.342 us; speedup vs baseline: 1.9767x; 1.0539x over previous
//
#include <hip/hip_runtime.h>
#include <hip/hip_bf16.h>

#define BATCH 4
#define SEQ   2048
#define EMB   1024
#define HD    64
#define BT    (BATCH * SEQ)
#define XS_STRIDE 1040   // dword stride 520 = 8 mod 32

// logits scale 1/sqrt(64) folded with log2(e) so softmax can use exp2 directly
#define QSCALE 0.18033688011112042f

typedef __attribute__((ext_vector_type(8))) short bf16x8;
typedef __attribute__((ext_vector_type(4))) float f32x4;

__device__ __forceinline__ ushort f2bf(float f) {   // RTN fp32 -> bf16 bits
    unsigned u = __float_as_uint(f);
    return (ushort)((u + 0x7FFFu + ((u >> 16) & 1u)) >> 16);
}

// ---- prep: Wf = W in MFMA B-fragment order [kc(32)][sub(12)][lane(64)][8] --
// frag element (lane,j): row = sub*16 + (lane&15), e = kc*32 + (lane>>4)*8 + j
__global__ __launch_bounds__(256) void prep(
    const float* __restrict__ Wq, const float* __restrict__ bq,
    const float* __restrict__ Wk, const float* __restrict__ bk,
    const float* __restrict__ Wv, const float* __restrict__ bv,
    ushort* __restrict__ Wf, float* __restrict__ bb)
{
    const int fid = (int)blockIdx.x * 256 + (int)threadIdx.x;   // 0..24575
    const int kc   = fid / 768;
    const int rem  = fid - kc * 768;
    const int sub  = rem >> 6;
    const int lane = rem & 63;
    const int row  = (sub & 3) * 16 + (lane & 15);
    const int e0   = kc * 32 + (lane >> 4) * 8;
    const float* W = (sub < 4) ? Wq : ((sub < 8) ? Wk : Wv);
    const float4 a0 = *(const float4*)(W + (size_t)row * EMB + e0);
    const float4 a1 = *(const float4*)(W + (size_t)row * EMB + e0 + 4);
    bf16x8 w;
    w[0] = (short)f2bf(a0.x); w[1] = (short)f2bf(a0.y);
    w[2] = (short)f2bf(a0.z); w[3] = (short)f2bf(a0.w);
    w[4] = (short)f2bf(a1.x); w[5] = (short)f2bf(a1.y);
    w[6] = (short)f2bf(a1.z); w[7] = (short)f2bf(a1.w);
    *(bf16x8*)(Wf + (size_t)fid * 8) = w;
    if (blockIdx.x == 0 && threadIdx.x < 192) {
        const int i = (int)threadIdx.x;
        const float* B = (i < 64) ? bq : ((i < 128) ? bk : bv);
        bb[i] = B[i & 63];
    }
}

// ---- QKV GEMM v2 (round-1 proven): 32 rows/block, 8 waves =
// (sub-triple sg) x (kc-parity kp). kc-parity split gives each wave SIX
// independent accumulator chains (acc[2][3], 16 deep) -> MFMA latency hidden;
// the row-group variant (3 chains, 32 deep) measured 6 us slower. Each Wf
// fragment feeds TWO MFMAs. K-halved staging: half-1 x loads issued after
// barrier 1, fly under phase-0 compute. kc-parity partials reduced via LDS.
__global__ __launch_bounds__(512, 2) void qkv_gemm(
    const float* __restrict__ x, const ushort* __restrict__ Wf,
    const float* __restrict__ bb,
    ushort* __restrict__ Qf, ushort* __restrict__ Kf, ushort* __restrict__ Vf)
{
    const int t0   = (int)blockIdx.x * 32;
    const int tid  = (int)threadIdx.x;
    const int wv   = tid >> 6;
    const int lane = tid & 63;
    const int col  = lane & 15, quad = lane >> 4;
    const int sg   = wv >> 1;            // sub-triple 0..3
    const int kp   = wv & 1;             // kc parity
    const int sub0 = sg * 3;

    __shared__ ushort xs[32][XS_STRIDE];              // 66.6 KB
    __shared__ __align__(16) float red[4][64][24];    // 24.6 KB

    // ---- stage half 0 (cols 0..511): 32 rows x 512 fp32 -> bf16, coalesced
    float4 v0[8];
    #pragma unroll
    for (int i = 0; i < 8; ++i) {
        const int idx = i * 512 + tid;
        const int row = idx >> 7, c4 = idx & 127;
        v0[i] = *(const float4*)(x + (size_t)(t0 + row) * EMB + c4 * 4);
    }
    #pragma unroll
    for (int i = 0; i < 8; ++i) {
        const int idx = i * 512 + tid;
        const int row = idx >> 7, c4 = idx & 127;
        ushort4 pk;
        pk.x = f2bf(v0[i].x); pk.y = f2bf(v0[i].y);
        pk.z = f2bf(v0[i].z); pk.w = f2bf(v0[i].w);
        *(ushort4*)&xs[row][c4 * 4] = pk;
    }
    __syncthreads();

    // ---- issue half-1 loads now: they complete under phase-0 compute
    float4 v1[8];
    #pragma unroll
    for (int i = 0; i < 8; ++i) {
        const int idx = i * 512 + tid;
        const int row = idx >> 7, c4 = idx & 127;
        v1[i] = *(const float4*)(x + (size_t)(t0 + row) * EMB + 512 + c4 * 4);
    }

    f32x4 acc[2][3];
    #pragma unroll
    for (int rg = 0; rg < 2; ++rg)
        #pragma unroll
        for (int s = 0; s < 3; ++s) acc[rg][s] = (f32x4){0.f, 0.f, 0.f, 0.f};

    // ---- phase 0: kc = kp + 2t (all < 16, reads cols < 512 only)
    #pragma unroll 4
    for (int t = 0; t < 8; ++t) {
        const int kc = kp + 2 * t;
        const bf16x8 a0 = *(const bf16x8*)&xs[col][kc * 32 + quad * 8];
        const bf16x8 a1 = *(const bf16x8*)&xs[16 + col][kc * 32 + quad * 8];
        #pragma unroll
        for (int s = 0; s < 3; ++s) {
            const bf16x8 w = *(const bf16x8*)(Wf + ((size_t)(kc * 12 + sub0 + s) * 64 + lane) * 8);
            acc[0][s] = __builtin_amdgcn_mfma_f32_16x16x32_bf16(a0, w, acc[0][s], 0, 0, 0);
            acc[1][s] = __builtin_amdgcn_mfma_f32_16x16x32_bf16(a1, w, acc[1][s], 0, 0, 0);
        }
    }

    // ---- write half 1 (cols 512..1023: disjoint from phase-0 reads, no race)
    #pragma unroll
    for (int i = 0; i < 8; ++i) {
        const int idx = i * 512 + tid;
        const int row = idx >> 7, c4 = idx & 127;
        ushort4 pk;
        pk.x = f2bf(v1[i].x); pk.y = f2bf(v1[i].y);
        pk.z = f2bf(v1[i].z); pk.w = f2bf(v1[i].w);
        *(ushort4*)&xs[row][512 + c4 * 4] = pk;
    }
    __syncthreads();

    // ---- phase 1: kc = 16 + kp + 2t
    #pragma unroll 4
    for (int t = 0; t < 8; ++t) {
        const int kc = 16 + kp + 2 * t;
        const bf16x8 a0 = *(const bf16x8*)&xs[col][kc * 32 + quad * 8];
        const bf16x8 a1 = *(const bf16x8*)&xs[16 + col][kc * 32 + quad * 8];
        #pragma unroll
        for (int s = 0; s < 3; ++s) {
            const bf16x8 w = *(const bf16x8*)(Wf + ((size_t)(kc * 12 + sub0 + s) * 64 + lane) * 8);
            acc[0][s] = __builtin_amdgcn_mfma_f32_16x16x32_bf16(a0, w, acc[0][s], 0, 0, 0);
            acc[1][s] = __builtin_amdgcn_mfma_f32_16x16x32_bf16(a1, w, acc[1][s], 0, 0, 0);
        }
    }

    // ---- kc-parity reduce: kp=1 waves publish, kp=0 waves sum + epilogue
    if (kp) {
        #pragma unroll
        for (int rg = 0; rg < 2; ++rg)
            #pragma unroll
            for (int s = 0; s < 3; ++s)
                *(f32x4*)&red[sg][lane][(rg * 3 + s) * 4] = acc[rg][s];
    }
    __syncthreads();
    if (kp) return;
    #pragma unroll
    for (int rg = 0; rg < 2; ++rg)
        #pragma unroll
        for (int s = 0; s < 3; ++s)
            acc[rg][s] += *(const f32x4*)&red[sg][lane][(rg * 3 + s) * 4];

    // ---- epilogue: bias + write in fragment order, two 16-row groups
    #pragma unroll
    for (int rg = 0; rg < 2; ++rg) {
        const int tt0 = t0 + rg * 16;
        const int b   = tt0 >> 11;
        const int qt  = (tt0 >> 4) & 127;
        const int sgt = tt0 + quad * 4;               // first of 4 consecutive t/s
        const int itk = (sgt & (SEQ - 1)) >> 6;       // batch-LOCAL K-tile
        #pragma unroll
        for (int s = 0; s < 3; ++s) {
            const int sub  = sub0 + s;
            const int hrow = sub * 16 + col;
            const float bias = bb[hrow];
            if (sub < 4) {                            // Q (scaled)
                const int h = hrow;
                const int f = h >> 5, qd = (h >> 3) & 3, jj = h & 7;
                ushort* base = Qf + (((size_t)(b * 128 + qt) * 2 + f) * 64 + qd * 16 + quad * 4) * 8 + jj;
                #pragma unroll
                for (int i = 0; i < 4; ++i)
                    base[i * 8] = f2bf((acc[rg][s][i] + bias) * QSCALE);
            } else if (sub < 8) {                     // K
                const int h = hrow - 64;
                const int f = h >> 5, qd = (h >> 3) & 3, jj = h & 7;
                const size_t frag = ((size_t)(b * 32 + itk) * 4 + ((sgt >> 4) & 3)) * 2 + f;
                ushort* base = Kf + frag * 512 + ((size_t)((sgt & 15) + 16 * qd)) * 8 + jj;
                #pragma unroll
                for (int i = 0; i < 4; ++i)
                    base[i * 8] = f2bf(acc[rg][s][i] + bias);
            } else {                                  // V (B-frag of PV: n=h, k=s)
                const int h = hrow - 128;
                const int k0 = sgt & 63;
                const int f = k0 >> 5, qd = (k0 >> 3) & 3, j0 = k0 & 7;
                const size_t frag = ((size_t)(b * 32 + itk) * 4 + (h >> 4)) * 2 + f;
                ushort4 pk;
                pk.x = f2bf(acc[rg][s][0] + bias); pk.y = f2bf(acc[rg][s][1] + bias);
                pk.z = f2bf(acc[rg][s][2] + bias); pk.w = f2bf(acc[rg][s][3] + bias);
                *(ushort4*)(Vf + frag * 512 + ((size_t)((h & 15) + 16 * qd)) * 8 + j0) = pk;
            }
        }
    }
}

// ---- attention (round-1 proven): 256 blocks x 8 waves, 32 Q rows/block.
// Each K/V fragment load feeds 32 MFMAs (2 Q tiles). 8-way K split; waves are
// independent inside the loop (no barrier) -> s_setprio around MFMA clusters
// (T5: measured regime). In-block LDS merge of 8 partials.
__global__ __launch_bounds__(512, 2) void attn(
    const ushort* __restrict__ Qf, const ushort* __restrict__ Kf,
    const ushort* __restrict__ Vf, float* __restrict__ out)
{
    const int blk  = (int)blockIdx.x;                 // 0..255
    const int b    = blk & 3;
    const int tl   = 63 - (blk >> 2);                 // longest tiles first
    const int t0   = tl * 32;
    const int nt   = ((t0 + 31) >> 6) + 1;            // K-tiles of 64 covering s<=t0+31
    const int tid  = (int)threadIdx.x;
    const int j    = tid >> 6;                        // wave = split index (0..7)
    const int lane = tid & 63;
    const int col  = lane & 15, quad = lane >> 4;

    const ushort* QbA = Qf + ((size_t)(b * 128 + 2 * tl) * 2) * 512;
    const bf16x8 aqA0 = *(const bf16x8*)(QbA + (size_t)lane * 8);
    const bf16x8 aqA1 = *(const bf16x8*)(QbA + 512 + (size_t)lane * 8);
    const bf16x8 aqB0 = *(const bf16x8*)(QbA + 1024 + (size_t)lane * 8);
    const bf16x8 aqB1 = *(const bf16x8*)(QbA + 1536 + (size_t)lane * 8);

    float l_a[4], l_b[4];                             // per-LANE partial sums
    f32x4 o[8];                                       // [0..3]=tileA, [4..7]=tileB
    #pragma unroll
    for (int i = 0; i < 4; ++i) { l_a[i] = 0.f; l_b[i] = 0.f; }
    #pragma unroll
    for (int i = 0; i < 8; ++i) o[i] = (f32x4){0.f, 0.f, 0.f, 0.f};

    __shared__ ushort pt[8][32][80];                  // per-wave P transpose tile
    __shared__ __align__(16) float op[8][32][68];     // per-wave O partial
    __shared__ float ll[8][32];

    // prologue: K fragments for first tile (only if this wave has work)
    bf16x8 kc[4][2];
    if (j < nt) {
        const ushort* Kt = Kf + ((size_t)(b * 32 + j) * 8) * 512;
        #pragma unroll
        for (int sub = 0; sub < 4; ++sub) {
            kc[sub][0] = *(const bf16x8*)(Kt + (size_t)(sub * 2 + 0) * 512 + (size_t)lane * 8);
            kc[sub][1] = *(const bf16x8*)(Kt + (size_t)(sub * 2 + 1) * 512 + (size_t)lane * 8);
        }
    }

    for (int it = j; it < nt; it += 8) {
        const int s0 = it * 64;
        const bool hasNext = (it + 8 < nt);

        // ---- S = (q*scale) . k^T for both Q tiles from current K fragments
        f32x4 scA[4], scB[4];
        __builtin_amdgcn_s_setprio(1);
        #pragma unroll
        for (int sub = 0; sub < 4; ++sub) {
            f32x4 z = {0.f, 0.f, 0.f, 0.f};
            z = __builtin_amdgcn_mfma_f32_16x16x32_bf16(aqA0, kc[sub][0], z, 0, 0, 0);
            z = __builtin_amdgcn_mfma_f32_16x16x32_bf16(aqA1, kc[sub][1], z, 0, 0, 0);
            scA[sub] = z;
            f32x4 y = {0.f, 0.f, 0.f, 0.f};
            y = __builtin_amdgcn_mfma_f32_16x16x32_bf16(aqB0, kc[sub][0], y, 0, 0, 0);
            y = __builtin_amdgcn_mfma_f32_16x16x32_bf16(aqB1, kc[sub][1], y, 0, 0, 0);
            scB[sub] = y;
        }
        __builtin_amdgcn_s_setprio(0);

        // ---- issue V(cur), then K(next) only if a next iter exists
        bf16x8 kn[4][2], vf[4][2];
        {
            const ushort* Vt = Vf + ((size_t)(b * 32 + it) * 8) * 512;
            #pragma unroll
            for (int sub = 0; sub < 4; ++sub) {
                vf[sub][0] = *(const bf16x8*)(Vt + (size_t)(sub * 2 + 0) * 512 + (size_t)lane * 8);
                vf[sub][1] = *(const bf16x8*)(Vt + (size_t)(sub * 2 + 1) * 512 + (size_t)lane * 8);
            }
        }
        if (hasNext) {
            const ushort* Kt = Kf + ((size_t)(b * 32 + it + 8) * 8) * 512;
            #pragma unroll
            for (int sub = 0; sub < 4; ++sub) {
                kn[sub][0] = *(const bf16x8*)(Kt + (size_t)(sub * 2 + 0) * 512 + (size_t)lane * 8);
                kn[sub][1] = *(const bf16x8*)(Kt + (size_t)(sub * 2 + 1) * 512 + (size_t)lane * 8);
            }
        }

        if (it == nt - 1) {                           // only the diagonal tile masks
            #pragma unroll
            for (int sub = 0; sub < 4; ++sub)
                #pragma unroll
                for (int i = 0; i < 4; ++i) {
                    const int s  = s0 + sub * 16 + col;
                    const int tA = t0 + quad * 4 + i;
                    if (s > tA)      scA[sub][i] = -1e30f;   // exp2 -> 0
                    if (s > tA + 16) scB[sub][i] = -1e30f;
                }
        }

        // ---- p = exp2(sc); accumulate l per-lane; stage P for transpose
        #pragma unroll
        for (int sub = 0; sub < 4; ++sub)
            #pragma unroll
            for (int i = 0; i < 4; ++i) {
                const float pA = exp2f(scA[sub][i]);
                l_a[i] += pA;
                pt[j][quad * 4 + i][sub * 16 + col] = f2bf(pA);
                const float pB = exp2f(scB[sub][i]);
                l_b[i] += pB;
                pt[j][16 + quad * 4 + i][sub * 16 + col] = f2bf(pB);
            }

        // ---- P: C/D -> A-operand via LDS (same-wave: waitcnt only, no barrier)
        __asm__ volatile("s_waitcnt lgkmcnt(0)" ::: "memory");
        const bf16x8 apA0 = *(const bf16x8*)&pt[j][col][quad * 8];
        const bf16x8 apA1 = *(const bf16x8*)&pt[j][col][32 + quad * 8];
        const bf16x8 apB0 = *(const bf16x8*)&pt[j][16 + col][quad * 8];
        const bf16x8 apB1 = *(const bf16x8*)&pt[j][16 + col][32 + quad * 8];

        // ---- O += P @ V from prefetched V fragments (shared by both tiles)
        __builtin_amdgcn_s_setprio(1);
        #pragma unroll
        for (int sub = 0; sub < 4; ++sub) {
            o[sub]     = __builtin_amdgcn_mfma_f32_16x16x32_bf16(apA0, vf[sub][0], o[sub], 0, 0, 0);
            o[sub]     = __builtin_amdgcn_mfma_f32_16x16x32_bf16(apA1, vf[sub][1], o[sub], 0, 0, 0);
            o[4 + sub] = __builtin_amdgcn_mfma_f32_16x16x32_bf16(apB0, vf[sub][0], o[4 + sub], 0, 0, 0);
            o[4 + sub] = __builtin_amdgcn_mfma_f32_16x16x32_bf16(apB1, vf[sub][1], o[4 + sub], 0, 0, 0);
        }
        __builtin_amdgcn_s_setprio(0);

        // ---- rotate K
        if (hasNext) {
            #pragma unroll
            for (int sub = 0; sub < 4; ++sub) { kc[sub][0] = kn[sub][0]; kc[sub][1] = kn[sub][1]; }
        }
    }

    // ---- one butterfly for l (sum over the 16 lanes of each quad-row group)
    #pragma unroll
    for (int d = 1; d < 16; d <<= 1)
        #pragma unroll
        for (int i = 0; i < 4; ++i) {
            l_a[i] += __shfl_xor(l_a[i], d, 64);
            l_b[i] += __shfl_xor(l_b[i], d, 64);
        }

    // ---- publish per-wave partial to LDS (waves with no work publish zeros)
    #pragma unroll
    for (int sub = 0; sub < 4; ++sub)
        #pragma unroll
        for (int i = 0; i < 4; ++i) {
            op[j][quad * 4 + i][sub * 16 + col]      = o[sub][i];
            op[j][16 + quad * 4 + i][sub * 16 + col] = o[4 + sub][i];
        }
    if (col == 0) {
        #pragma unroll
        for (int i = 0; i < 4; ++i) {
            ll[j][quad * 4 + i]      = l_a[i];
            ll[j][16 + quad * 4 + i] = l_b[i];
        }
    }
    __syncthreads();

    // ---- merge 8 wave-partials: thread = (row 0..31, 4-col group); direct write
    {
        const int row = tid >> 4, c0 = (tid & 15) * 4;
        float sx = 0.f, sy = 0.f, sz = 0.f, sw = 0.f, ls = 0.f;
        #pragma unroll
        for (int w = 0; w < 8; ++w) {
            const float4 p = *(const float4*)&op[w][row][c0];
            sx += p.x; sy += p.y; sz += p.z; sw += p.w;
            ls += ll[w][row];
        }
        const float rinv = 1.0f / ls;
        float4 res;
        res.x = sx * rinv; res.y = sy * rinv; res.z = sz * rinv; res.w = sw * rinv;
        *(float4*)(out + ((size_t)b * SEQ + t0 + row) * HD + c0) = res;
    }
}

extern "C" void kernel_launch(void* const* d_in, const int* in_sizes, int n_in,
                              void* d_out, int out_size, void* d_ws, size_t ws_size,
                              hipStream_t stream)
{
    const float* x  = (const float*)d_in[0];
    const float* Wq = (const float*)d_in[1];
    const float* bq = (const float*)d_in[2];
    const float* Wk = (const float*)d_in[3];
    const float* bk = (const float*)d_in[4];
    const float* Wv = (const float*)d_in[5];
    const float* bv = (const float*)d_in[6];
    float* out = (float*)d_out;

    char* ws = (char*)d_ws;
    ushort* Wf  = (ushort*)(ws);                        // 384 KB
    float*  bb  = (float*)(ws + 0x60000);               // 768 B
    ushort* Qfb = (ushort*)(ws + 0x61000);              // 1 MB
    ushort* Kfb = (ushort*)(ws + 0x161000);             // 1 MB
    ushort* Vfb = (ushort*)(ws + 0x261000);             // 1 MB

    prep<<<96, 256, 0, stream>>>(Wq, bq, Wk, bk, Wv, bv, Wf, bb);
    qkv_gemm<<<BT / 32, 512, 0, stream>>>(x, Wf, bb, Qfb, Kfb, Vfb);
    attn<<<256, 512, 0, stream>>>(Qfb, Kfb, Vfb, out);
}